// Round 2
// baseline (1429.802 us; speedup 1.0000x reference)
//
#include <hip/hip_runtime.h>
#include <stdint.h>

typedef unsigned short u16;
typedef __bf16 bf16x8 __attribute__((ext_vector_type(8)));
typedef float f32x4 __attribute__((ext_vector_type(4)));

#define NNODES 150000
#define KNBR 27
#define LDX 128
#define MROWS 64
#define APAD 72   // LDS row stride in u16 (144 B): A-frag ds_read_b128 -> 2-way alias only (free)

static __device__ __forceinline__ u16 f2bf(float f){
  union { float f; uint32_t i; } v; v.f = f;
  uint32_t x = v.i;
  uint32_t r = (x + 0x7fffu + ((x >> 16) & 1u)) >> 16;  // RNE
  return (u16)r;
}
static __device__ __forceinline__ float lrelu(float v){ return v >= 0.f ? v : 0.2f*v; }

// Reformat fp32 weight (krows x 64, row-major) into bf16 MFMA B-fragment order:
// dst[t][ctile][lane][j] = bf16(src[(t*32 + (lane>>4)*8 + j)*64 + ctile*16 + (lane&15)])
__global__ void reformat_w(const float* __restrict__ src, u16* __restrict__ dst, int ksteps){
  int idx = blockIdx.x*256 + threadIdx.x;
  int total = ksteps*4*64;
  if (idx >= total) return;
  int lane = idx & 63;
  int ctile = (idx >> 6) & 3;
  int t = idx >> 8;
  int quad = lane >> 4, m = lane & 15;
  union { u16 h[8]; float4 v; } tmp;
  const float* s = src + ((size_t)(t*32 + quad*8))*64 + ctile*16 + m;
  #pragma unroll
  for (int j=0;j<8;j++) tmp.h[j] = f2bf(s[j*64]);
  *reinterpret_cast<float4*>(dst + (size_t)idx*8) = tmp.v;
}

// u_g = lrelu(lrelu(gather(src) @ w1g) @ w2g), same for h (shared gather).
// src fp32 (ld floats, offset floats); ug/uh bf16 (N x 64).
__global__ __launch_bounds__(256) void conv1_fused(
    const float* __restrict__ src, int src_ld, int src_off,
    const int* __restrict__ nbr,
    const u16* __restrict__ wb1g, const u16* __restrict__ wb1h,
    const u16* __restrict__ wb2g, const u16* __restrict__ wb2h,
    u16* __restrict__ ug, u16* __restrict__ uh)
{
  __shared__ int s_idx[MROWS*KNBR];
  __shared__ u16 s_a[2][MROWS*APAD];

  int tid = threadIdx.x;
  int row0 = blockIdx.x * MROWS;
  for (int i = tid; i < MROWS*KNBR; i += 256){
    int r = i / KNBR, kk = i - r*KNBR;
    int row = row0 + r;
    s_idx[i] = (row < NNODES) ? nbr[row*KNBR + kk] : 0;
  }
  __syncthreads();

  int lane = tid & 63;
  int wv = tid >> 6;
  int quad = lane >> 4, m = lane & 15;
  int r0w = wv * 16;

  f32x4 accg[4], acch[4];
  f32x4 zz = {0.f,0.f,0.f,0.f};
  #pragma unroll
  for (int i=0;i<4;i++){ accg[i]=zz; acch[i]=zz; }

  // gather: each thread owns 16 consecutive floats of one row (4 threads/row)
  int gr = tid >> 2;          // row in tile 0..63
  int gq = (tid & 3) * 16;    // col offset (floats / bf16 elems)

  float4 p[4];
  {
    int f = s_idx[gr*KNBR];
    const float* s0 = src + (size_t)f*src_ld + src_off + gq;
    p[0] = *reinterpret_cast<const float4*>(s0);
    p[1] = *reinterpret_cast<const float4*>(s0+4);
    p[2] = *reinterpret_cast<const float4*>(s0+8);
    p[3] = *reinterpret_cast<const float4*>(s0+12);
  }

  for (int k=0;k<KNBR;k++){
    {
      union { u16 h[16]; float4 v[2]; } tmp;
      #pragma unroll
      for (int e=0;e<4;e++){
        tmp.h[e*4+0]=f2bf(p[e].x); tmp.h[e*4+1]=f2bf(p[e].y);
        tmp.h[e*4+2]=f2bf(p[e].z); tmp.h[e*4+3]=f2bf(p[e].w);
      }
      *reinterpret_cast<float4*>(&s_a[0][gr*APAD + gq])     = tmp.v[0];
      *reinterpret_cast<float4*>(&s_a[0][gr*APAD + gq + 8]) = tmp.v[1];
    }
    __syncthreads();
    if (k+1 < KNBR){
      int f = s_idx[gr*KNBR + k+1];
      const float* s0 = src + (size_t)f*src_ld + src_off + gq;
      p[0] = *reinterpret_cast<const float4*>(s0);
      p[1] = *reinterpret_cast<const float4*>(s0+4);
      p[2] = *reinterpret_cast<const float4*>(s0+8);
      p[3] = *reinterpret_cast<const float4*>(s0+12);
    }
    #pragma unroll
    for (int c=0;c<2;c++){
      bf16x8 afrag = *reinterpret_cast<const bf16x8*>(&s_a[0][(r0w+m)*APAD + c*32 + quad*8]);
      int t = k*2 + c;
      #pragma unroll
      for (int ct=0;ct<4;ct++){
        bf16x8 bg = *reinterpret_cast<const bf16x8*>(wb1g + (((size_t)t*4+ct)*64 + lane)*8);
        accg[ct] = __builtin_amdgcn_mfma_f32_16x16x32_bf16(afrag, bg, accg[ct], 0,0,0);
        bf16x8 bh = *reinterpret_cast<const bf16x8*>(wb1h + (((size_t)t*4+ct)*64 + lane)*8);
        acch[ct] = __builtin_amdgcn_mfma_f32_16x16x32_bf16(afrag, bh, acch[ct], 0,0,0);
      }
    }
    __syncthreads();
  }

  // epilogue: lrelu -> bf16 tiles in LDS (C-layout -> A-layout round trip)
  #pragma unroll
  for (int ct=0;ct<4;ct++){
    #pragma unroll
    for (int i=0;i<4;i++){
      int rl = r0w + quad*4 + i;
      int col = ct*16 + m;
      s_a[0][rl*APAD + col] = f2bf(lrelu(accg[ct][i]));
      s_a[1][rl*APAD + col] = f2bf(lrelu(acch[ct][i]));
    }
  }
  __syncthreads();

  f32x4 dg[4], dh[4];
  #pragma unroll
  for (int i=0;i<4;i++){ dg[i]=zz; dh[i]=zz; }
  #pragma unroll
  for (int c=0;c<2;c++){
    bf16x8 ag = *reinterpret_cast<const bf16x8*>(&s_a[0][(r0w+m)*APAD + c*32 + quad*8]);
    bf16x8 ah = *reinterpret_cast<const bf16x8*>(&s_a[1][(r0w+m)*APAD + c*32 + quad*8]);
    #pragma unroll
    for (int ct=0;ct<4;ct++){
      bf16x8 bg = *reinterpret_cast<const bf16x8*>(wb2g + (((size_t)c*4+ct)*64 + lane)*8);
      dg[ct] = __builtin_amdgcn_mfma_f32_16x16x32_bf16(ag, bg, dg[ct], 0,0,0);
      bf16x8 bh = *reinterpret_cast<const bf16x8*>(wb2h + (((size_t)c*4+ct)*64 + lane)*8);
      dh[ct] = __builtin_amdgcn_mfma_f32_16x16x32_bf16(ah, bh, dh[ct], 0,0,0);
    }
  }
  #pragma unroll
  for (int ct=0;ct<4;ct++){
    #pragma unroll
    for (int i=0;i<4;i++){
      int row = row0 + r0w + quad*4 + i;
      if (row < NNODES){
        int col = ct*16 + m;
        ug[(size_t)row*64 + col] = f2bf(lrelu(dg[ct][i]));
        uh[(size_t)row*64 + col] = f2bf(lrelu(dh[ct][i]));
      }
    }
  }
}

// bg = gather(ug) @ w3g ; bh = gather(uh) @ w3h ; y = x_prev * exp(2*sigmoid(bg)-1) + bh
// ug/uh bf16; x, out fp32 (LDX cols).
__global__ __launch_bounds__(256) void conv2_coupling(
    const u16* __restrict__ ug, const u16* __restrict__ uh,
    const int* __restrict__ nbr,
    const u16* __restrict__ wbg, const u16* __restrict__ wbh,
    const float* __restrict__ x, int xcol0,
    float* __restrict__ out, int ycol0)
{
  __shared__ int s_idx[MROWS*KNBR];
  __shared__ u16 s_g[MROWS*APAD];
  __shared__ u16 s_h[MROWS*APAD];

  int tid = threadIdx.x;
  int row0 = blockIdx.x * MROWS;
  for (int i = tid; i < MROWS*KNBR; i += 256){
    int r = i / KNBR, kk = i - r*KNBR;
    int row = row0 + r;
    s_idx[i] = (row < NNODES) ? nbr[row*KNBR + kk] : 0;
  }
  __syncthreads();

  int lane = tid & 63;
  int wv = tid >> 6;
  int quad = lane >> 4, m = lane & 15;
  int r0w = wv * 16;

  f32x4 accg[4], acch[4];
  f32x4 zz = {0.f,0.f,0.f,0.f};
  #pragma unroll
  for (int i=0;i<4;i++){ accg[i]=zz; acch[i]=zz; }

  // gather bf16 rows: 8 u16 (16B) per thread per source, 2 chunks cover 64x64
  int gr0 = tid >> 3,            gs0 = (tid & 7) * 8;
  int gr1 = (tid + 256) >> 3,    gs1 = gs0;

  float4 pg0, pg1, ph0, ph1;
  {
    int f0 = s_idx[gr0*KNBR], f1 = s_idx[gr1*KNBR];
    pg0 = *reinterpret_cast<const float4*>(ug + (size_t)f0*64 + gs0);
    pg1 = *reinterpret_cast<const float4*>(ug + (size_t)f1*64 + gs1);
    ph0 = *reinterpret_cast<const float4*>(uh + (size_t)f0*64 + gs0);
    ph1 = *reinterpret_cast<const float4*>(uh + (size_t)f1*64 + gs1);
  }

  for (int k=0;k<KNBR;k++){
    *reinterpret_cast<float4*>(&s_g[gr0*APAD + gs0]) = pg0;
    *reinterpret_cast<float4*>(&s_g[gr1*APAD + gs1]) = pg1;
    *reinterpret_cast<float4*>(&s_h[gr0*APAD + gs0]) = ph0;
    *reinterpret_cast<float4*>(&s_h[gr1*APAD + gs1]) = ph1;
    __syncthreads();
    if (k+1 < KNBR){
      int f0 = s_idx[gr0*KNBR + k+1], f1 = s_idx[gr1*KNBR + k+1];
      pg0 = *reinterpret_cast<const float4*>(ug + (size_t)f0*64 + gs0);
      pg1 = *reinterpret_cast<const float4*>(ug + (size_t)f1*64 + gs1);
      ph0 = *reinterpret_cast<const float4*>(uh + (size_t)f0*64 + gs0);
      ph1 = *reinterpret_cast<const float4*>(uh + (size_t)f1*64 + gs1);
    }
    #pragma unroll
    for (int c=0;c<2;c++){
      bf16x8 ag = *reinterpret_cast<const bf16x8*>(&s_g[(r0w+m)*APAD + c*32 + quad*8]);
      bf16x8 ah = *reinterpret_cast<const bf16x8*>(&s_h[(r0w+m)*APAD + c*32 + quad*8]);
      int t = k*2 + c;
      #pragma unroll
      for (int ct=0;ct<4;ct++){
        bf16x8 bg = *reinterpret_cast<const bf16x8*>(wbg + (((size_t)t*4+ct)*64 + lane)*8);
        accg[ct] = __builtin_amdgcn_mfma_f32_16x16x32_bf16(ag, bg, accg[ct], 0,0,0);
        bf16x8 bh = *reinterpret_cast<const bf16x8*>(wbh + (((size_t)t*4+ct)*64 + lane)*8);
        acch[ct] = __builtin_amdgcn_mfma_f32_16x16x32_bf16(ah, bh, acch[ct], 0,0,0);
      }
    }
    __syncthreads();
  }

  #pragma unroll
  for (int ct=0;ct<4;ct++){
    #pragma unroll
    for (int i=0;i<4;i++){
      int row = row0 + r0w + quad*4 + i;
      if (row < NNODES){
        int col = ct*16 + m;
        float bg = accg[ct][i];
        float bh = acch[ct][i];
        float s = 1.f/(1.f + __expf(-bg));
        s = __expf(2.f*s - 1.f);
        float xv = x[(size_t)row*LDX + xcol0 + col];
        out[(size_t)row*LDX + ycol0 + col] = xv*s + bh;
      }
    }
  }
}

extern "C" void kernel_launch(void* const* d_in, const int* in_sizes, int n_in,
                              void* d_out, int out_size, void* d_ws, size_t ws_size,
                              hipStream_t stream)
{
  const float* x   = (const float*)d_in[0];
  const int*   nbr = (const int*)d_in[1];
  const float* g1_w1=(const float*)d_in[2],  *g1_w2=(const float*)d_in[3],  *g1_w3=(const float*)d_in[4];
  const float* g2_w1=(const float*)d_in[5],  *g2_w2=(const float*)d_in[6],  *g2_w3=(const float*)d_in[7];
  const float* h1_w1=(const float*)d_in[8],  *h1_w2=(const float*)d_in[9],  *h1_w3=(const float*)d_in[10];
  const float* h2_w1=(const float*)d_in[11], *h2_w2=(const float*)d_in[12], *h2_w3=(const float*)d_in[13];
  float* out = (float*)d_out;
  u16* ws = (u16*)d_ws;

  const size_t WBB = (size_t)54*4*64*8;  // 1728-row weights (bf16 frags)
  const size_t WBS = (size_t)2*4*64*8;   // 64-row weights
  u16* p = ws;
  u16* wb_g2_1=p; p+=WBB;  u16* wb_h2_1=p; p+=WBB;
  u16* wb_g2_2=p; p+=WBS;  u16* wb_h2_2=p; p+=WBS;
  u16* wb_g2_3=p; p+=WBB;  u16* wb_h2_3=p; p+=WBB;
  u16* wb_g1_1=p; p+=WBB;  u16* wb_h1_1=p; p+=WBB;
  u16* wb_g1_2=p; p+=WBS;  u16* wb_h1_2=p; p+=WBS;
  u16* wb_g1_3=p; p+=WBB;  u16* wb_h1_3=p; p+=WBB;
  u16* ug = p; p += (size_t)NNODES*64;
  u16* uh = p; p += (size_t)NNODES*64;

  reformat_w<<<54,256,0,stream>>>(g2_w1, wb_g2_1, 54);
  reformat_w<<<54,256,0,stream>>>(h2_w1, wb_h2_1, 54);
  reformat_w<<<2,256,0,stream>>>(g2_w2, wb_g2_2, 2);
  reformat_w<<<2,256,0,stream>>>(h2_w2, wb_h2_2, 2);
  reformat_w<<<54,256,0,stream>>>(g2_w3, wb_g2_3, 54);
  reformat_w<<<54,256,0,stream>>>(h2_w3, wb_h2_3, 54);
  reformat_w<<<54,256,0,stream>>>(g1_w1, wb_g1_1, 54);
  reformat_w<<<54,256,0,stream>>>(h1_w1, wb_h1_1, 54);
  reformat_w<<<2,256,0,stream>>>(g1_w2, wb_g1_2, 2);
  reformat_w<<<2,256,0,stream>>>(h1_w2, wb_h1_2, 2);
  reformat_w<<<54,256,0,stream>>>(g1_w3, wb_g1_3, 54);
  reformat_w<<<54,256,0,stream>>>(h1_w3, wb_h1_3, 54);

  int nblk = (NNODES + MROWS - 1)/MROWS;  // 2344
  // Phase A: src = x2 (fp32 cols 64..127); y1 -> out cols 0..63
  conv1_fused<<<nblk,256,0,stream>>>(x, LDX, 64, nbr, wb_g2_1, wb_h2_1, wb_g2_2, wb_h2_2, ug, uh);
  conv2_coupling<<<nblk,256,0,stream>>>(ug, uh, nbr, wb_g2_3, wb_h2_3, x, 0, out, 0);
  // Phase B: src = y1 (out fp32 cols 0..63); y2 -> out cols 64..127
  conv1_fused<<<nblk,256,0,stream>>>(out, LDX, 0, nbr, wb_g1_1, wb_h1_1, wb_g1_2, wb_h1_2, ug, uh);
  conv2_coupling<<<nblk,256,0,stream>>>(ug, uh, nbr, wb_g1_3, wb_h1_3, x, 64, out, 64);
}